// Round 1
// 389.647 us; speedup vs baseline: 1.0221x; 1.0221x over previous
//
#include <hip/hip_runtime.h>
#include <hip/hip_bf16.h>
#include <hip/hip_fp16.h>
#include <cmath>

// PREFFFT: masked-spectrum iFFT2 (3 planes x 128ch x 256x256) + bilinear
// grid-sample at 262144 points + 8-term Fourier integration -> (N,16).
//
// R6 (gather was VALU-issue-bound: 105us @ ~105% VALUBusy, 13% HBM):
// (1) feat stored as fp16*16384 (better mantissa than bf16; scale folded
//     into bilerp weights) and the r-dot done FIRST with v_dot2_f32_f16:
//     16 dot2 + 4 fma replaces 32 unpack ops + 20 pk-fma.
// (2) scatter precomputes per-point pixel offset + edge flags + wx/wy
//     (half2) + (s+1)*0.996 into psort -> gather does no floor/clamp math.
// (3) all shuffles via immediate ds_swizzle (no bpermute addr setup).
// (4) combine folded into gather via atomicAdd(out) -> one kernel fewer,
//     ~117MB of partial traffic removed (out is memset at launch).

#define NPTS 262144

typedef _Float16 f16x2 __attribute__((ext_vector_type(2)));

__device__ __forceinline__ int brev8(int x) { return (int)(__brev((unsigned)x) >> 24); }

__device__ __forceinline__ unsigned pack_bf16(float2 v) {
    unsigned short a = __builtin_bit_cast(unsigned short, __float2bfloat16(v.x));
    unsigned short b = __builtin_bit_cast(unsigned short, __float2bfloat16(v.y));
    return (unsigned)a | ((unsigned)b << 16);
}
__device__ __forceinline__ float2 unpack_bf16(unsigned u) {
    return make_float2(__uint_as_float(u << 16), __uint_as_float(u & 0xffff0000u));
}

__device__ __forceinline__ float dot2f(unsigned a, unsigned b, float c) {
#if __has_builtin(__builtin_amdgcn_fdot2)
    return __builtin_amdgcn_fdot2(__builtin_bit_cast(f16x2, a),
                                  __builtin_bit_cast(f16x2, b), c, false);
#else
    float d;
    asm("v_dot2_f32_f16 %0, %1, %2, %3" : "=v"(d) : "v"(a), "v"(b), "v"(c));
    return d;
#endif
}

// plane coordinate mapping (matches reference):
// p=0: gx=in1 gy=in2 s=in0 | p=1: gx=in0 gy=in2 s=in1 | p=2: gx=in0 gy=in1 s=in2
__device__ __forceinline__ void plane_coords(int p, float in0, float in1, float in2,
                                             float& gx, float& gy, float& sc) {
    gx = (p == 0) ? in1 : in0;
    gy = (p == 2) ? in1 : in2;
    sc = (p == 0) ? in0 : ((p == 1) ? in1 : in2);
}

// ---------------- Pass 1: iFFT over y for each (plane, ch, x<128) column ---
// Cooperative load/store; butterfly stages wave-private (wave w: cols 2w,2w+1).
__global__ __launch_bounds__(512) void pass1_kernel(const float* __restrict__ P0,
                                                    const float* __restrict__ P1,
                                                    const float* __restrict__ P2,
                                                    unsigned* __restrict__ X) {
    __shared__ float2 tw[128];
    __shared__ float2 tile[256 * 17];

    int t = threadIdx.x;
    if (t < 128) {
        float s, c;
        sincospif((float)t * (1.0f / 128.0f), &s, &c);
        tw[t] = make_float2(c, s);
    }
    int plane = blockIdx.y;
    const float* P = (plane == 0) ? P0 : ((plane == 1) ? P1 : P2);
    unsigned* Xp = X + (size_t)plane * 4194304;

    int b  = blockIdx.x;
    int ch = b >> 3;
    int x0 = (b & 7) << 4;
    const float* src = P + (size_t)ch * 131072 + x0 * 2;

    const float scale = 1.0f / 65536.0f;
#pragma unroll
    for (int k = 0; k < 2; k++) {
        int i = t + (k << 9);
        int y = i >> 3;
        int j = i & 7;
        float4 v = *(const float4*)(src + (size_t)y * 512 + (j << 2));
        float2 c0 = make_float2(v.x * scale, v.y * scale);
        float2 c1 = make_float2(v.z * scale, v.w * scale);
        int pos = brev8(y);             // even; writing pos and pos+1 folds stage 1
        tile[pos * 17 + 2 * j]           = c0;
        tile[(pos + 1) * 17 + 2 * j]     = c0;
        tile[pos * 17 + 2 * j + 1]       = c1;
        tile[(pos + 1) * 17 + 2 * j + 1] = c1;
    }
    __syncthreads();

    int w = t >> 6, l = t & 63;
    int col = (w << 1) + (l & 1);       // wave-private column
    int bb  = l >> 1;                   // 0..31
#pragma unroll
    for (int s = 2; s <= 8; s++) {
        int half = 1 << (s - 1);
#pragma unroll
        for (int k = 0; k < 4; k++) {
            int bf = bb + (k << 5);     // 0..127
            int j  = bf & (half - 1);
            int g  = bf >> (s - 1);
            int i0 = (g << s) + j;
            int i1 = i0 + half;
            float2 u = tile[i0 * 17 + col];
            float2 v = tile[i1 * 17 + col];
            float2 wq = tw[j << (8 - s)];
            float2 vt = make_float2(v.x * wq.x - v.y * wq.y, v.x * wq.y + v.y * wq.x);
            tile[i0 * 17 + col] = make_float2(u.x + vt.x, u.y + vt.y);
            tile[i1 * 17 + col] = make_float2(u.x - vt.x, u.y - vt.y);
        }
        // wave-private: no barrier between stages
    }
    __syncthreads();

    unsigned* dst = Xp + (size_t)ch * 32768 + x0;
#pragma unroll
    for (int k = 0; k < 8; k++) {
        int i = t + (k << 9);
        int v = i >> 4;
        int c = i & 15;
        dst[(size_t)v * 128 + c] = pack_bf16(tile[v * 17 + c]);
    }
}

// ---------------- Pass 2: iFFT over x, store feat as fp16*16384 -------------
// Rows are wave-private: no per-stage barriers.
__global__ __launch_bounds__(1024) void pass2_kernel(const unsigned* __restrict__ X,
                                                     __half* __restrict__ feat) {
    __shared__ float2 tw[128];
    __shared__ float2 rows[16 * 257];

    int t = threadIdx.x;
    if (t < 128) {
        float s, c;
        sincospif((float)t * (1.0f / 128.0f), &s, &c);
        tw[t] = make_float2(c, s);
    }
    int w = t >> 6;
    int l = t & 63;
    int v   = blockIdx.x & 255;
    int g   = blockIdx.x >> 8;
    int ch0 = g << 4;
    int ch  = ch0 + w;
    int plane = blockIdx.y;
    const unsigned* Xp = X + (size_t)plane * 4194304;
    __half* fp = feat + (size_t)plane * 16777216;

    const uint2* src = (const uint2*)(Xp + ((size_t)ch * 256 + v) * 128);
    uint2 d = src[l];
    float2 c0 = unpack_bf16(d.x);
    float2 c1 = unpack_bf16(d.y);
    float2* row = rows + w * 257;
    int p0 = brev8(2 * l);
    int p1 = brev8(2 * l + 1);
    row[p0]     = c0;
    row[p0 + 1] = c0;
    row[p1]     = c1;
    row[p1 + 1] = c1;
    __syncthreads();                    // covers tw init (rows are wave-private)
#pragma unroll
    for (int s = 2; s <= 8; s++) {
        int half = 1 << (s - 1);
#pragma unroll
        for (int k = 0; k < 2; k++) {
            int bf = l + (k << 6);
            int j  = bf & (half - 1);
            int gg = bf >> (s - 1);
            int i0 = (gg << s) + j;
            int i1 = i0 + half;
            float2 u  = row[i0];
            float2 vv = row[i1];
            float2 wq = tw[j << (8 - s)];
            float2 vt = make_float2(vv.x * wq.x - vv.y * wq.y,
                                    vv.x * wq.y + vv.y * wq.x);
            row[i0] = make_float2(u.x + vt.x, u.y + vt.y);
            row[i1] = make_float2(u.x - vt.x, u.y - vt.y);
        }
        // wave-private: no barrier
    }
    __syncthreads();                    // epilogue reads other waves' rows
    __half* dst = fp + (size_t)v * 65536 + (ch0 << 1);
#pragma unroll
    for (int k = 0; k < 8; k++) {
        int f = t + (k << 10);
        int x = f >> 5;
        int j = f & 31;
        float2 cpx = rows[(j >> 1) * 257 + x];
        float val = (j & 1) ? cpx.y : cpx.x;
        dst[x * 256 + j] = __float2half(val * 16384.0f);
    }
}

// ---------------- Sort: histogram / scan / scatter --------------------------
__device__ __forceinline__ int tile_key(float gx, float gy) {
    float xf = (gx + 1.0f) * 127.5f;
    float yf = (gy + 1.0f) * 127.5f;
    int x0 = max(0, min((int)floorf(xf), 255));
    int y0 = max(0, min((int)floorf(yf), 255));
    return (y0 & 0xF0) | (x0 >> 4);
}

__global__ __launch_bounds__(1024) void hist_kernel(const float* __restrict__ pts,
                                                    unsigned* __restrict__ hist) {
    __shared__ unsigned hb[256];
    int t = threadIdx.x;
    int p = blockIdx.y;
    int n = (blockIdx.x << 10) + t;
    if (t < 256) hb[t] = 0;
    __syncthreads();
    float in0 = pts[3 * n + 0], in1 = pts[3 * n + 1], in2 = pts[3 * n + 2];
    float gx, gy, sc;
    plane_coords(p, in0, in1, in2, gx, gy, sc);
    atomicAdd(&hb[tile_key(gx, gy)], 1u);
    __syncthreads();
    if (t < 256 && hb[t]) atomicAdd(&hist[(p << 8) + t], hb[t]);
}

__global__ __launch_bounds__(256) void scan_kernel(const unsigned* __restrict__ hist,
                                                   unsigned* __restrict__ cursor) {
    __shared__ unsigned s[256];
    int t = threadIdx.x;
    for (int p = 0; p < 3; p++) {
        unsigned v = hist[(p << 8) + t];
        s[t] = v;
        __syncthreads();
#pragma unroll
        for (int d = 1; d < 256; d <<= 1) {
            unsigned add = (t >= d) ? s[t - d] : 0u;
            __syncthreads();
            s[t] += add;
            __syncthreads();
        }
        cursor[(p << 8) + t] = s[t] - v;   // exclusive prefix
        __syncthreads();
    }
}

// writes per-plane sorted point table:
// (packed pixel-offset+edge-flags, wx|wy half2, (s+1)*0.996, bitcast(n))
__global__ __launch_bounds__(1024) void scatter_kernel(const float* __restrict__ pts,
                                                       unsigned* __restrict__ cursor,
                                                       float4* __restrict__ psort) {
    __shared__ unsigned cnt[256];
    __shared__ unsigned base[256];
    int t = threadIdx.x;
    int p = blockIdx.y;
    int n = (blockIdx.x << 10) + t;
    if (t < 256) cnt[t] = 0;
    __syncthreads();
    float in0 = pts[3 * n + 0], in1 = pts[3 * n + 1], in2 = pts[3 * n + 2];
    float gx, gy, sc;
    plane_coords(p, in0, in1, in2, gx, gy, sc);

    float xf = (gx + 1.0f) * 127.5f;
    float yf = (gy + 1.0f) * 127.5f;
    float x0f = floorf(xf);
    float y0f = floorf(yf);
    float wx = xf - x0f;
    float wy = yf - y0f;
    int x0 = max(0, min((int)x0f, 255));
    int y0 = max(0, min((int)y0f, 255));
    int key = (y0 & 0xF0) | (x0 >> 4);

    unsigned rank = atomicAdd(&cnt[key], 1u);
    __syncthreads();
    if (t < 256 && cnt[t]) base[t] = atomicAdd(&cursor[(p << 8) + t], cnt[t]);
    __syncthreads();

    unsigned pk = ((unsigned)((y0 << 8) + x0) << 8)
                | ((x0 < 255) ? (1u << 24) : 0u)
                | ((y0 < 255) ? (1u << 25) : 0u);
    float sprime = (sc + 1.0f) * 0.99609375f;
    __half2 wh = __floats2half2_rn(wx, wy);
    psort[p * NPTS + base[key] + rank] =
        make_float4(__uint_as_float(pk), __builtin_bit_cast(float, wh),
                    sprime, __int_as_float(n));
}

// ---------------- Gather (sorted, XCD-chunk swizzled) -----------------------
// dot2-first: per corner, dot the lane's 8 fp16 values with the 8 fp16
// Fourier weights (4 x v_dot2_f32_f16), then 4-corner bilerp combine.
// 3 planes accumulate into out via atomicAdd (combine kernel removed).
__global__ __launch_bounds__(256) void gather_kernel(const ushort* __restrict__ feat,
                                                     const float4* __restrict__ psort,
                                                     float* __restrict__ out) {
    int t = threadIdx.x;
    int w = t >> 6;
    int l = t & 63;
    int h = l >> 5;                     // point within wave
    int q = l & 31;                     // owns feature bytes 16q..16q+15
    int p = blockIdx.y;
    const ushort* fb = feat + (size_t)p * 16777216;

    // XCD swizzle: dispatch b -> XCD b%8; give each XCD one contiguous chunk
    int b  = blockIdx.x;                        // 0..32767
    int lb = ((b & 7) << 12) | (b >> 3);        // logical sorted block
    int idx = (lb << 3) + (w << 1) + h;
    float4 pt = psort[p * NPTS + idx];

    unsigned pk = __float_as_uint(pt.x);
    __half2 wh = __builtin_bit_cast(__half2, pt.y);
    float wx = __low2float(wh);
    float wy = __high2float(wh);
    float s1 = pt.z;
    int n = __float_as_int(pt.w);

    unsigned bpoff = pk & 0xFFFFFFu;
    int dx = (int)((pk >> 16) & 0x100u);        // +1 px in x = 256 ushorts
    int dy = (int)((pk >> 9) & 0x10000u);       // +1 px in y = 65536 ushorts

    const ushort* bp = fb + bpoff + (q << 3);
    uint4 d00 = *(const uint4*)bp;
    uint4 d01 = *(const uint4*)(bp + dx);
    uint4 d10 = *(const uint4*)(bp + dy);
    uint4 d11 = *(const uint4*)(bp + dx + dy);

    // Fourier weights: lane with r=q&7 computes theta_r; pack fp16 pairs and
    // broadcast via immediate ds_swizzle (lane -> (l&16)|2j within each half)
    float coef = (float)((1 << (q & 7)) - 1);
    float a = s1 * coef;                        // theta/pi
    float sn, cs;
    sincospif(a, &sn, &cs);
    float merged = (q < 16) ? cs : -sn;
    float partner = __int_as_float(
        __builtin_amdgcn_ds_swizzle(__float_as_int(merged), 0x041F)); // lane^1
    float lo = (l & 1) ? partner : merged;
    float hi = (l & 1) ? merged : partner;
    __half2 wp = __floats2half2_rn(lo, hi);
    unsigned wpi = __builtin_bit_cast(unsigned, wp);
    unsigned w0 = (unsigned)__builtin_amdgcn_ds_swizzle((int)wpi, 0x0010); // (l&16)|0
    unsigned w1 = (unsigned)__builtin_amdgcn_ds_swizzle((int)wpi, 0x0050); // (l&16)|2
    unsigned w2 = (unsigned)__builtin_amdgcn_ds_swizzle((int)wpi, 0x0090); // (l&16)|4
    unsigned w3 = (unsigned)__builtin_amdgcn_ds_swizzle((int)wpi, 0x00D0); // (l&16)|6

    float s00 = dot2f(d00.w, w3, dot2f(d00.z, w2, dot2f(d00.y, w1, dot2f(d00.x, w0, 0.0f))));
    float s01 = dot2f(d01.w, w3, dot2f(d01.z, w2, dot2f(d01.y, w1, dot2f(d01.x, w0, 0.0f))));
    float s10 = dot2f(d10.w, w3, dot2f(d10.z, w2, dot2f(d10.y, w1, dot2f(d10.x, w0, 0.0f))));
    float s11 = dot2f(d11.w, w3, dot2f(d11.z, w2, dot2f(d11.y, w1, dot2f(d11.x, w0, 0.0f))));

    const float INV = 6.103515625e-05f;         // 1/16384: undo feat scaling
    float wys = wy * INV;
    float wyc = INV - wys;                      // (1-wy)*INV
    float wxc = 1.0f - wx;
    float acc = s00 * (wxc * wyc);
    acc = fmaf(s01, wx * wyc, acc);
    acc = fmaf(s10, wxc * wys, acc);
    acc = fmaf(s11, wx * wys, acc);

    acc += __int_as_float(
        __builtin_amdgcn_ds_swizzle(__float_as_int(acc), 0x401F)); // lane^16
    if (q < 16) {
        atomicAdd(&out[((size_t)n << 4) + q], acc);
    }
}

extern "C" void kernel_launch(void* const* d_in, const int* in_sizes, int n_in,
                              void* d_out, int out_size, void* d_ws, size_t ws_size,
                              hipStream_t stream) {
    const float* P0  = (const float*)d_in[0];
    const float* P1  = (const float*)d_in[1];
    const float* P2  = (const float*)d_in[2];
    const float* pts = (const float*)d_in[3];
    float* out = (float*)d_out;
    char* ws = (char*)d_ws;

    // ws layout (bytes):
    __half*   feat   = (__half*)ws;                                // 100,663,296
    unsigned* X      = (unsigned*)(ws + 100663296u);               //  50,331,648
    float4*   psort  = (float4*)(ws + 201326592u);                 //  12,582,912
    unsigned* hist   = (unsigned*)(ws + 213909504u);               //       3,072
    unsigned* cursor = (unsigned*)(ws + 213912576u);               //       3,072

    hipMemsetAsync(hist, 0, 3072, stream);
    hipMemsetAsync(out, 0, (size_t)NPTS * 64, stream);             // 16,777,216

    dim3 g1(1024, 3);
    pass1_kernel<<<g1, 512, 0, stream>>>(P0, P1, P2, X);
    dim3 g2(2048, 3);
    pass2_kernel<<<g2, 1024, 0, stream>>>(X, feat);

    dim3 gs(256, 3);
    hist_kernel<<<gs, 1024, 0, stream>>>(pts, hist);
    scan_kernel<<<1, 256, 0, stream>>>(hist, cursor);
    scatter_kernel<<<gs, 1024, 0, stream>>>(pts, cursor, psort);

    dim3 gg(32768, 3);
    gather_kernel<<<gg, 256, 0, stream>>>((const ushort*)feat, psort, out);
}

// Round 2
// 359.166 us; speedup vs baseline: 1.1089x; 1.0849x over previous
//
#include <hip/hip_runtime.h>
#include <hip/hip_bf16.h>
#include <hip/hip_fp16.h>
#include <cmath>

// PREFFFT: masked-spectrum iFFT2 (3 planes x 128ch x 256x256) + bilinear
// grid-sample at 262144 points + 8-term Fourier integration -> (N,16).
//
// R7 (pass2 was LDS-bank-conflict bound: 99us, 2.32e7 conflict cycles,
// VALUBusy 31%): XOR-swizzle LDS element slots swz(i)=(i&~15)|((i^(i>>4))&15)
// for the FFT rows/tiles AND the twiddle table; stage-4 butterflies (the one
// stage a single XOR hash cannot spread) use a remapped lane->butterfly
// assignment (bf=2l+k / bf=4bb+k), making every butterfly stage, the
// bit-reversed init store, and the epilogue reads uniform (4 lanes per
// bank-pair = b64 throughput minimum). Same math, same element sets.

#define NPTS 262144

typedef _Float16 f16x2 __attribute__((ext_vector_type(2)));

__device__ __forceinline__ int brev8(int x) { return (int)(__brev((unsigned)x) >> 24); }

// bank-pair spreading bijection within each 16-element block
__device__ __forceinline__ int swz(int i) {
    return (i & ~15) | ((i ^ (i >> 4)) & 15);
}

__device__ __forceinline__ unsigned pack_bf16(float2 v) {
    unsigned short a = __builtin_bit_cast(unsigned short, __float2bfloat16(v.x));
    unsigned short b = __builtin_bit_cast(unsigned short, __float2bfloat16(v.y));
    return (unsigned)a | ((unsigned)b << 16);
}
__device__ __forceinline__ float2 unpack_bf16(unsigned u) {
    return make_float2(__uint_as_float(u << 16), __uint_as_float(u & 0xffff0000u));
}

__device__ __forceinline__ float dot2f(unsigned a, unsigned b, float c) {
#if __has_builtin(__builtin_amdgcn_fdot2)
    return __builtin_amdgcn_fdot2(__builtin_bit_cast(f16x2, a),
                                  __builtin_bit_cast(f16x2, b), c, false);
#else
    float d;
    asm("v_dot2_f32_f16 %0, %1, %2, %3" : "=v"(d) : "v"(a), "v"(b), "v"(c));
    return d;
#endif
}

// plane coordinate mapping (matches reference):
// p=0: gx=in1 gy=in2 s=in0 | p=1: gx=in0 gy=in2 s=in1 | p=2: gx=in0 gy=in1 s=in2
__device__ __forceinline__ void plane_coords(int p, float in0, float in1, float in2,
                                             float& gx, float& gy, float& sc) {
    gx = (p == 0) ? in1 : in0;
    gy = (p == 2) ? in1 : in2;
    sc = (p == 0) ? in0 : ((p == 1) ? in1 : in2);
}

// ---------------- Pass 1: iFFT over y for each (plane, ch, x<128) column ---
// Cooperative load/store; butterfly stages wave-private (wave w: cols 2w,2w+1).
__global__ __launch_bounds__(512) void pass1_kernel(const float* __restrict__ P0,
                                                    const float* __restrict__ P1,
                                                    const float* __restrict__ P2,
                                                    unsigned* __restrict__ X) {
    __shared__ float2 tw[128];
    __shared__ float2 tile[256 * 17];

    int t = threadIdx.x;
    if (t < 128) {
        float s, c;
        sincospif((float)t * (1.0f / 128.0f), &s, &c);
        tw[swz(t)] = make_float2(c, s);
    }
    int plane = blockIdx.y;
    const float* P = (plane == 0) ? P0 : ((plane == 1) ? P1 : P2);
    unsigned* Xp = X + (size_t)plane * 4194304;

    int b  = blockIdx.x;
    int ch = b >> 3;
    int x0 = (b & 7) << 4;
    const float* src = P + (size_t)ch * 131072 + x0 * 2;

    const float scale = 1.0f / 65536.0f;
#pragma unroll
    for (int k = 0; k < 2; k++) {
        int i = t + (k << 9);
        int y = i >> 3;
        int j = i & 7;
        float4 v = *(const float4*)(src + (size_t)y * 512 + (j << 2));
        float2 c0 = make_float2(v.x * scale, v.y * scale);
        float2 c1 = make_float2(v.z * scale, v.w * scale);
        int pos = brev8(y);             // even; writing pos and pos+1 folds stage 1
        tile[swz(pos) * 17 + 2 * j]           = c0;
        tile[swz(pos + 1) * 17 + 2 * j]       = c0;
        tile[swz(pos) * 17 + 2 * j + 1]       = c1;
        tile[swz(pos + 1) * 17 + 2 * j + 1]   = c1;
    }
    __syncthreads();

    int w = t >> 6, l = t & 63;
    int col = (w << 1) + (l & 1);       // wave-private column
    int bb  = l >> 1;                   // 0..31
#pragma unroll
    for (int s = 2; s <= 8; s++) {
        int half = 1 << (s - 1);
#pragma unroll
        for (int k = 0; k < 4; k++) {
            // stage 4: remapped butterfly assignment (conflict-free under swz)
            int bf = (s == 4) ? ((bb << 2) + k) : (bb + (k << 5));
            int j  = bf & (half - 1);
            int g  = bf >> (s - 1);
            int i0 = (g << s) + j;
            int i1 = i0 + half;
            float2 u = tile[swz(i0) * 17 + col];
            float2 v = tile[swz(i1) * 17 + col];
            float2 wq = tw[swz(j << (8 - s))];
            float2 vt = make_float2(v.x * wq.x - v.y * wq.y, v.x * wq.y + v.y * wq.x);
            tile[swz(i0) * 17 + col] = make_float2(u.x + vt.x, u.y + vt.y);
            tile[swz(i1) * 17 + col] = make_float2(u.x - vt.x, u.y - vt.y);
        }
        // wave-private: no barrier between stages
    }
    __syncthreads();

    unsigned* dst = Xp + (size_t)ch * 32768 + x0;
#pragma unroll
    for (int k = 0; k < 8; k++) {
        int i = t + (k << 9);
        int v = i >> 4;
        int c = i & 15;
        dst[(size_t)v * 128 + c] = pack_bf16(tile[swz(v) * 17 + c]);
    }
}

// ---------------- Pass 2: iFFT over x, store feat as fp16*16384 -------------
// Rows are wave-private: no per-stage barriers.
__global__ __launch_bounds__(1024) void pass2_kernel(const unsigned* __restrict__ X,
                                                     __half* __restrict__ feat) {
    __shared__ float2 tw[128];
    __shared__ float2 rows[16 * 257];

    int t = threadIdx.x;
    if (t < 128) {
        float s, c;
        sincospif((float)t * (1.0f / 128.0f), &s, &c);
        tw[swz(t)] = make_float2(c, s);
    }
    int w = t >> 6;
    int l = t & 63;
    int v   = blockIdx.x & 255;
    int g   = blockIdx.x >> 8;
    int ch0 = g << 4;
    int ch  = ch0 + w;
    int plane = blockIdx.y;
    const unsigned* Xp = X + (size_t)plane * 4194304;
    __half* fp = feat + (size_t)plane * 16777216;

    const uint2* src = (const uint2*)(Xp + ((size_t)ch * 256 + v) * 128);
    uint2 d = src[l];
    float2 c0 = unpack_bf16(d.x);
    float2 c1 = unpack_bf16(d.y);
    float2* row = rows + w * 257;
    int p0 = brev8(2 * l);
    int p1 = brev8(2 * l + 1);
    row[swz(p0)]     = c0;
    row[swz(p0 + 1)] = c0;
    row[swz(p1)]     = c1;
    row[swz(p1 + 1)] = c1;
    __syncthreads();                    // covers tw init (rows are wave-private)
#pragma unroll
    for (int s = 2; s <= 8; s++) {
        int half = 1 << (s - 1);
#pragma unroll
        for (int k = 0; k < 2; k++) {
            // stage 4: remapped butterfly assignment (conflict-free under swz)
            int bf = (s == 4) ? ((l << 1) + k) : (l + (k << 6));
            int j  = bf & (half - 1);
            int gg = bf >> (s - 1);
            int i0 = (gg << s) + j;
            int i1 = i0 + half;
            float2 u  = row[swz(i0)];
            float2 vv = row[swz(i1)];
            float2 wq = tw[swz(j << (8 - s))];
            float2 vt = make_float2(vv.x * wq.x - vv.y * wq.y,
                                    vv.x * wq.y + vv.y * wq.x);
            row[swz(i0)] = make_float2(u.x + vt.x, u.y + vt.y);
            row[swz(i1)] = make_float2(u.x - vt.x, u.y - vt.y);
        }
        // wave-private: no barrier
    }
    __syncthreads();                    // epilogue reads other waves' rows
    __half* dst = fp + (size_t)v * 65536 + (ch0 << 1);
#pragma unroll
    for (int k = 0; k < 8; k++) {
        int f = t + (k << 10);
        int x = f >> 5;
        int j = f & 31;
        float2 cpx = rows[(j >> 1) * 257 + swz(x)];
        float val = (j & 1) ? cpx.y : cpx.x;
        dst[x * 256 + j] = __float2half(val * 16384.0f);
    }
}

// ---------------- Sort: histogram / scan / scatter --------------------------
__device__ __forceinline__ int tile_key(float gx, float gy) {
    float xf = (gx + 1.0f) * 127.5f;
    float yf = (gy + 1.0f) * 127.5f;
    int x0 = max(0, min((int)floorf(xf), 255));
    int y0 = max(0, min((int)floorf(yf), 255));
    return (y0 & 0xF0) | (x0 >> 4);
}

__global__ __launch_bounds__(1024) void hist_kernel(const float* __restrict__ pts,
                                                    unsigned* __restrict__ hist) {
    __shared__ unsigned hb[256];
    int t = threadIdx.x;
    int p = blockIdx.y;
    int n = (blockIdx.x << 10) + t;
    if (t < 256) hb[t] = 0;
    __syncthreads();
    float in0 = pts[3 * n + 0], in1 = pts[3 * n + 1], in2 = pts[3 * n + 2];
    float gx, gy, sc;
    plane_coords(p, in0, in1, in2, gx, gy, sc);
    atomicAdd(&hb[tile_key(gx, gy)], 1u);
    __syncthreads();
    if (t < 256 && hb[t]) atomicAdd(&hist[(p << 8) + t], hb[t]);
}

__global__ __launch_bounds__(256) void scan_kernel(const unsigned* __restrict__ hist,
                                                   unsigned* __restrict__ cursor) {
    __shared__ unsigned s[256];
    int t = threadIdx.x;
    for (int p = 0; p < 3; p++) {
        unsigned v = hist[(p << 8) + t];
        s[t] = v;
        __syncthreads();
#pragma unroll
        for (int d = 1; d < 256; d <<= 1) {
            unsigned add = (t >= d) ? s[t - d] : 0u;
            __syncthreads();
            s[t] += add;
            __syncthreads();
        }
        cursor[(p << 8) + t] = s[t] - v;   // exclusive prefix
        __syncthreads();
    }
}

// writes per-plane sorted point table:
// (packed pixel-offset+edge-flags, wx|wy half2, (s+1)*0.996, bitcast(n))
__global__ __launch_bounds__(1024) void scatter_kernel(const float* __restrict__ pts,
                                                       unsigned* __restrict__ cursor,
                                                       float4* __restrict__ psort) {
    __shared__ unsigned cnt[256];
    __shared__ unsigned base[256];
    int t = threadIdx.x;
    int p = blockIdx.y;
    int n = (blockIdx.x << 10) + t;
    if (t < 256) cnt[t] = 0;
    __syncthreads();
    float in0 = pts[3 * n + 0], in1 = pts[3 * n + 1], in2 = pts[3 * n + 2];
    float gx, gy, sc;
    plane_coords(p, in0, in1, in2, gx, gy, sc);

    float xf = (gx + 1.0f) * 127.5f;
    float yf = (gy + 1.0f) * 127.5f;
    float x0f = floorf(xf);
    float y0f = floorf(yf);
    float wx = xf - x0f;
    float wy = yf - y0f;
    int x0 = max(0, min((int)x0f, 255));
    int y0 = max(0, min((int)y0f, 255));
    int key = (y0 & 0xF0) | (x0 >> 4);

    unsigned rank = atomicAdd(&cnt[key], 1u);
    __syncthreads();
    if (t < 256 && cnt[t]) base[t] = atomicAdd(&cursor[(p << 8) + t], cnt[t]);
    __syncthreads();

    unsigned pk = ((unsigned)((y0 << 8) + x0) << 8)
                | ((x0 < 255) ? (1u << 24) : 0u)
                | ((y0 < 255) ? (1u << 25) : 0u);
    float sprime = (sc + 1.0f) * 0.99609375f;
    __half2 wh = __floats2half2_rn(wx, wy);
    psort[p * NPTS + base[key] + rank] =
        make_float4(__uint_as_float(pk), __builtin_bit_cast(float, wh),
                    sprime, __int_as_float(n));
}

// ---------------- Gather (sorted, XCD-chunk swizzled) -----------------------
// dot2-first: per corner, dot the lane's 8 fp16 values with the 8 fp16
// Fourier weights (4 x v_dot2_f32_f16), then 4-corner bilerp combine.
// 3 planes accumulate into out via atomicAdd (combine kernel removed).
__global__ __launch_bounds__(256) void gather_kernel(const ushort* __restrict__ feat,
                                                     const float4* __restrict__ psort,
                                                     float* __restrict__ out) {
    int t = threadIdx.x;
    int w = t >> 6;
    int l = t & 63;
    int h = l >> 5;                     // point within wave
    int q = l & 31;                     // owns feature bytes 16q..16q+15
    int p = blockIdx.y;
    const ushort* fb = feat + (size_t)p * 16777216;

    // XCD swizzle: dispatch b -> XCD b%8; give each XCD one contiguous chunk
    int b  = blockIdx.x;                        // 0..32767
    int lb = ((b & 7) << 12) | (b >> 3);        // logical sorted block
    int idx = (lb << 3) + (w << 1) + h;
    float4 pt = psort[p * NPTS + idx];

    unsigned pk = __float_as_uint(pt.x);
    __half2 wh = __builtin_bit_cast(__half2, pt.y);
    float wx = __low2float(wh);
    float wy = __high2float(wh);
    float s1 = pt.z;
    int n = __float_as_int(pt.w);

    unsigned bpoff = pk & 0xFFFFFFu;
    int dx = (int)((pk >> 16) & 0x100u);        // +1 px in x = 256 ushorts
    int dy = (int)((pk >> 9) & 0x10000u);       // +1 px in y = 65536 ushorts

    const ushort* bp = fb + bpoff + (q << 3);
    uint4 d00 = *(const uint4*)bp;
    uint4 d01 = *(const uint4*)(bp + dx);
    uint4 d10 = *(const uint4*)(bp + dy);
    uint4 d11 = *(const uint4*)(bp + dx + dy);

    // Fourier weights: lane with r=q&7 computes theta_r; pack fp16 pairs and
    // broadcast via immediate ds_swizzle (lane -> (l&16)|2j within each half)
    float coef = (float)((1 << (q & 7)) - 1);
    float a = s1 * coef;                        // theta/pi
    float sn, cs;
    sincospif(a, &sn, &cs);
    float merged = (q < 16) ? cs : -sn;
    float partner = __int_as_float(
        __builtin_amdgcn_ds_swizzle(__float_as_int(merged), 0x041F)); // lane^1
    float lo = (l & 1) ? partner : merged;
    float hi = (l & 1) ? merged : partner;
    __half2 wp = __floats2half2_rn(lo, hi);
    unsigned wpi = __builtin_bit_cast(unsigned, wp);
    unsigned w0 = (unsigned)__builtin_amdgcn_ds_swizzle((int)wpi, 0x0010); // (l&16)|0
    unsigned w1 = (unsigned)__builtin_amdgcn_ds_swizzle((int)wpi, 0x0050); // (l&16)|2
    unsigned w2 = (unsigned)__builtin_amdgcn_ds_swizzle((int)wpi, 0x0090); // (l&16)|4
    unsigned w3 = (unsigned)__builtin_amdgcn_ds_swizzle((int)wpi, 0x00D0); // (l&16)|6

    float s00 = dot2f(d00.w, w3, dot2f(d00.z, w2, dot2f(d00.y, w1, dot2f(d00.x, w0, 0.0f))));
    float s01 = dot2f(d01.w, w3, dot2f(d01.z, w2, dot2f(d01.y, w1, dot2f(d01.x, w0, 0.0f))));
    float s10 = dot2f(d10.w, w3, dot2f(d10.z, w2, dot2f(d10.y, w1, dot2f(d10.x, w0, 0.0f))));
    float s11 = dot2f(d11.w, w3, dot2f(d11.z, w2, dot2f(d11.y, w1, dot2f(d11.x, w0, 0.0f))));

    const float INV = 6.103515625e-05f;         // 1/16384: undo feat scaling
    float wys = wy * INV;
    float wyc = INV - wys;                      // (1-wy)*INV
    float wxc = 1.0f - wx;
    float acc = s00 * (wxc * wyc);
    acc = fmaf(s01, wx * wyc, acc);
    acc = fmaf(s10, wxc * wys, acc);
    acc = fmaf(s11, wx * wys, acc);

    acc += __int_as_float(
        __builtin_amdgcn_ds_swizzle(__float_as_int(acc), 0x401F)); // lane^16
    if (q < 16) {
        atomicAdd(&out[((size_t)n << 4) + q], acc);
    }
}

extern "C" void kernel_launch(void* const* d_in, const int* in_sizes, int n_in,
                              void* d_out, int out_size, void* d_ws, size_t ws_size,
                              hipStream_t stream) {
    const float* P0  = (const float*)d_in[0];
    const float* P1  = (const float*)d_in[1];
    const float* P2  = (const float*)d_in[2];
    const float* pts = (const float*)d_in[3];
    float* out = (float*)d_out;
    char* ws = (char*)d_ws;

    // ws layout (bytes):
    __half*   feat   = (__half*)ws;                                // 100,663,296
    unsigned* X      = (unsigned*)(ws + 100663296u);               //  50,331,648
    float4*   psort  = (float4*)(ws + 201326592u);                 //  12,582,912
    unsigned* hist   = (unsigned*)(ws + 213909504u);               //       3,072
    unsigned* cursor = (unsigned*)(ws + 213912576u);               //       3,072

    hipMemsetAsync(hist, 0, 3072, stream);
    hipMemsetAsync(out, 0, (size_t)NPTS * 64, stream);             // 16,777,216

    dim3 g1(1024, 3);
    pass1_kernel<<<g1, 512, 0, stream>>>(P0, P1, P2, X);
    dim3 g2(2048, 3);
    pass2_kernel<<<g2, 1024, 0, stream>>>(X, feat);

    dim3 gs(256, 3);
    hist_kernel<<<gs, 1024, 0, stream>>>(pts, hist);
    scan_kernel<<<1, 256, 0, stream>>>(hist, cursor);
    scatter_kernel<<<gs, 1024, 0, stream>>>(pts, cursor, psort);

    dim3 gg(32768, 3);
    gather_kernel<<<gg, 256, 0, stream>>>((const ushort*)feat, psort, out);
}

// Round 3
// 346.828 us; speedup vs baseline: 1.1483x; 1.0356x over previous
//
#include <hip/hip_runtime.h>
#include <hip/hip_bf16.h>
#include <hip/hip_fp16.h>
#include <cmath>

// PREFFFT: masked-spectrum iFFT2 (3 planes x 128ch x 256x256) + bilinear
// grid-sample at 262144 points + 8-term Fourier integration -> (N,16).
//
// R8 (gather was latency-bound: 113us, VALUBusy 65%, HBM 12%, no LDS
// conflicts -> one point in flight per half-wave, serial
// load->sincos->swizzle->dot chain): 4-point software pipeline per wave.
// Each block now covers 32 consecutive sorted points (grid 8192); the 4
// psort entries load up front and STAGE(i+1) (feat loads) issues before
// WORK(i) (weights+dot2+bilerp+atomic), so point i's compute hides point
// i+1's memory latency. Same per-point math, just reordered.

#define NPTS 262144

typedef _Float16 f16x2 __attribute__((ext_vector_type(2)));

__device__ __forceinline__ int brev8(int x) { return (int)(__brev((unsigned)x) >> 24); }

// bank-pair spreading bijection within each 16-element block
__device__ __forceinline__ int swz(int i) {
    return (i & ~15) | ((i ^ (i >> 4)) & 15);
}

__device__ __forceinline__ unsigned pack_bf16(float2 v) {
    unsigned short a = __builtin_bit_cast(unsigned short, __float2bfloat16(v.x));
    unsigned short b = __builtin_bit_cast(unsigned short, __float2bfloat16(v.y));
    return (unsigned)a | ((unsigned)b << 16);
}
__device__ __forceinline__ float2 unpack_bf16(unsigned u) {
    return make_float2(__uint_as_float(u << 16), __uint_as_float(u & 0xffff0000u));
}

__device__ __forceinline__ float dot2f(unsigned a, unsigned b, float c) {
#if __has_builtin(__builtin_amdgcn_fdot2)
    return __builtin_amdgcn_fdot2(__builtin_bit_cast(f16x2, a),
                                  __builtin_bit_cast(f16x2, b), c, false);
#else
    float d;
    asm("v_dot2_f32_f16 %0, %1, %2, %3" : "=v"(d) : "v"(a), "v"(b), "v"(c));
    return d;
#endif
}

// plane coordinate mapping (matches reference):
// p=0: gx=in1 gy=in2 s=in0 | p=1: gx=in0 gy=in2 s=in1 | p=2: gx=in0 gy=in1 s=in2
__device__ __forceinline__ void plane_coords(int p, float in0, float in1, float in2,
                                             float& gx, float& gy, float& sc) {
    gx = (p == 0) ? in1 : in0;
    gy = (p == 2) ? in1 : in2;
    sc = (p == 0) ? in0 : ((p == 1) ? in1 : in2);
}

// ---------------- Pass 1: iFFT over y for each (plane, ch, x<128) column ---
// Cooperative load/store; butterfly stages wave-private (wave w: cols 2w,2w+1).
__global__ __launch_bounds__(512) void pass1_kernel(const float* __restrict__ P0,
                                                    const float* __restrict__ P1,
                                                    const float* __restrict__ P2,
                                                    unsigned* __restrict__ X) {
    __shared__ float2 tw[128];
    __shared__ float2 tile[256 * 17];

    int t = threadIdx.x;
    if (t < 128) {
        float s, c;
        sincospif((float)t * (1.0f / 128.0f), &s, &c);
        tw[swz(t)] = make_float2(c, s);
    }
    int plane = blockIdx.y;
    const float* P = (plane == 0) ? P0 : ((plane == 1) ? P1 : P2);
    unsigned* Xp = X + (size_t)plane * 4194304;

    int b  = blockIdx.x;
    int ch = b >> 3;
    int x0 = (b & 7) << 4;
    const float* src = P + (size_t)ch * 131072 + x0 * 2;

    const float scale = 1.0f / 65536.0f;
#pragma unroll
    for (int k = 0; k < 2; k++) {
        int i = t + (k << 9);
        int y = i >> 3;
        int j = i & 7;
        float4 v = *(const float4*)(src + (size_t)y * 512 + (j << 2));
        float2 c0 = make_float2(v.x * scale, v.y * scale);
        float2 c1 = make_float2(v.z * scale, v.w * scale);
        int pos = brev8(y);             // even; writing pos and pos+1 folds stage 1
        tile[swz(pos) * 17 + 2 * j]           = c0;
        tile[swz(pos + 1) * 17 + 2 * j]       = c0;
        tile[swz(pos) * 17 + 2 * j + 1]       = c1;
        tile[swz(pos + 1) * 17 + 2 * j + 1]   = c1;
    }
    __syncthreads();

    int w = t >> 6, l = t & 63;
    int col = (w << 1) + (l & 1);       // wave-private column
    int bb  = l >> 1;                   // 0..31
#pragma unroll
    for (int s = 2; s <= 8; s++) {
        int half = 1 << (s - 1);
#pragma unroll
        for (int k = 0; k < 4; k++) {
            // stage 4: remapped butterfly assignment (conflict-free under swz)
            int bf = (s == 4) ? ((bb << 2) + k) : (bb + (k << 5));
            int j  = bf & (half - 1);
            int g  = bf >> (s - 1);
            int i0 = (g << s) + j;
            int i1 = i0 + half;
            float2 u = tile[swz(i0) * 17 + col];
            float2 v = tile[swz(i1) * 17 + col];
            float2 wq = tw[swz(j << (8 - s))];
            float2 vt = make_float2(v.x * wq.x - v.y * wq.y, v.x * wq.y + v.y * wq.x);
            tile[swz(i0) * 17 + col] = make_float2(u.x + vt.x, u.y + vt.y);
            tile[swz(i1) * 17 + col] = make_float2(u.x - vt.x, u.y - vt.y);
        }
        // wave-private: no barrier between stages
    }
    __syncthreads();

    unsigned* dst = Xp + (size_t)ch * 32768 + x0;
#pragma unroll
    for (int k = 0; k < 8; k++) {
        int i = t + (k << 9);
        int v = i >> 4;
        int c = i & 15;
        dst[(size_t)v * 128 + c] = pack_bf16(tile[swz(v) * 17 + c]);
    }
}

// ---------------- Pass 2: iFFT over x, store feat as fp16*16384 -------------
// Rows are wave-private: no per-stage barriers.
__global__ __launch_bounds__(1024) void pass2_kernel(const unsigned* __restrict__ X,
                                                     __half* __restrict__ feat) {
    __shared__ float2 tw[128];
    __shared__ float2 rows[16 * 257];

    int t = threadIdx.x;
    if (t < 128) {
        float s, c;
        sincospif((float)t * (1.0f / 128.0f), &s, &c);
        tw[swz(t)] = make_float2(c, s);
    }
    int w = t >> 6;
    int l = t & 63;
    int v   = blockIdx.x & 255;
    int g   = blockIdx.x >> 8;
    int ch0 = g << 4;
    int ch  = ch0 + w;
    int plane = blockIdx.y;
    const unsigned* Xp = X + (size_t)plane * 4194304;
    __half* fp = feat + (size_t)plane * 16777216;

    const uint2* src = (const uint2*)(Xp + ((size_t)ch * 256 + v) * 128);
    uint2 d = src[l];
    float2 c0 = unpack_bf16(d.x);
    float2 c1 = unpack_bf16(d.y);
    float2* row = rows + w * 257;
    int p0 = brev8(2 * l);
    int p1 = brev8(2 * l + 1);
    row[swz(p0)]     = c0;
    row[swz(p0 + 1)] = c0;
    row[swz(p1)]     = c1;
    row[swz(p1 + 1)] = c1;
    __syncthreads();                    // covers tw init (rows are wave-private)
#pragma unroll
    for (int s = 2; s <= 8; s++) {
        int half = 1 << (s - 1);
#pragma unroll
        for (int k = 0; k < 2; k++) {
            // stage 4: remapped butterfly assignment (conflict-free under swz)
            int bf = (s == 4) ? ((l << 1) + k) : (l + (k << 6));
            int j  = bf & (half - 1);
            int gg = bf >> (s - 1);
            int i0 = (gg << s) + j;
            int i1 = i0 + half;
            float2 u  = row[swz(i0)];
            float2 vv = row[swz(i1)];
            float2 wq = tw[swz(j << (8 - s))];
            float2 vt = make_float2(vv.x * wq.x - vv.y * wq.y,
                                    vv.x * wq.y + vv.y * wq.x);
            row[swz(i0)] = make_float2(u.x + vt.x, u.y + vt.y);
            row[swz(i1)] = make_float2(u.x - vt.x, u.y - vt.y);
        }
        // wave-private: no barrier
    }
    __syncthreads();                    // epilogue reads other waves' rows
    __half* dst = fp + (size_t)v * 65536 + (ch0 << 1);
#pragma unroll
    for (int k = 0; k < 8; k++) {
        int f = t + (k << 10);
        int x = f >> 5;
        int j = f & 31;
        float2 cpx = rows[(j >> 1) * 257 + swz(x)];
        float val = (j & 1) ? cpx.y : cpx.x;
        dst[x * 256 + j] = __float2half(val * 16384.0f);
    }
}

// ---------------- Sort: histogram / scan / scatter --------------------------
__device__ __forceinline__ int tile_key(float gx, float gy) {
    float xf = (gx + 1.0f) * 127.5f;
    float yf = (gy + 1.0f) * 127.5f;
    int x0 = max(0, min((int)floorf(xf), 255));
    int y0 = max(0, min((int)floorf(yf), 255));
    return (y0 & 0xF0) | (x0 >> 4);
}

__global__ __launch_bounds__(1024) void hist_kernel(const float* __restrict__ pts,
                                                    unsigned* __restrict__ hist) {
    __shared__ unsigned hb[256];
    int t = threadIdx.x;
    int p = blockIdx.y;
    int n = (blockIdx.x << 10) + t;
    if (t < 256) hb[t] = 0;
    __syncthreads();
    float in0 = pts[3 * n + 0], in1 = pts[3 * n + 1], in2 = pts[3 * n + 2];
    float gx, gy, sc;
    plane_coords(p, in0, in1, in2, gx, gy, sc);
    atomicAdd(&hb[tile_key(gx, gy)], 1u);
    __syncthreads();
    if (t < 256 && hb[t]) atomicAdd(&hist[(p << 8) + t], hb[t]);
}

__global__ __launch_bounds__(256) void scan_kernel(const unsigned* __restrict__ hist,
                                                   unsigned* __restrict__ cursor) {
    __shared__ unsigned s[256];
    int t = threadIdx.x;
    for (int p = 0; p < 3; p++) {
        unsigned v = hist[(p << 8) + t];
        s[t] = v;
        __syncthreads();
#pragma unroll
        for (int d = 1; d < 256; d <<= 1) {
            unsigned add = (t >= d) ? s[t - d] : 0u;
            __syncthreads();
            s[t] += add;
            __syncthreads();
        }
        cursor[(p << 8) + t] = s[t] - v;   // exclusive prefix
        __syncthreads();
    }
}

// writes per-plane sorted point table:
// (packed pixel-offset+edge-flags, wx|wy half2, (s+1)*0.996, bitcast(n))
__global__ __launch_bounds__(1024) void scatter_kernel(const float* __restrict__ pts,
                                                       unsigned* __restrict__ cursor,
                                                       float4* __restrict__ psort) {
    __shared__ unsigned cnt[256];
    __shared__ unsigned base[256];
    int t = threadIdx.x;
    int p = blockIdx.y;
    int n = (blockIdx.x << 10) + t;
    if (t < 256) cnt[t] = 0;
    __syncthreads();
    float in0 = pts[3 * n + 0], in1 = pts[3 * n + 1], in2 = pts[3 * n + 2];
    float gx, gy, sc;
    plane_coords(p, in0, in1, in2, gx, gy, sc);

    float xf = (gx + 1.0f) * 127.5f;
    float yf = (gy + 1.0f) * 127.5f;
    float x0f = floorf(xf);
    float y0f = floorf(yf);
    float wx = xf - x0f;
    float wy = yf - y0f;
    int x0 = max(0, min((int)x0f, 255));
    int y0 = max(0, min((int)y0f, 255));
    int key = (y0 & 0xF0) | (x0 >> 4);

    unsigned rank = atomicAdd(&cnt[key], 1u);
    __syncthreads();
    if (t < 256 && cnt[t]) base[t] = atomicAdd(&cursor[(p << 8) + t], cnt[t]);
    __syncthreads();

    unsigned pk = ((unsigned)((y0 << 8) + x0) << 8)
                | ((x0 < 255) ? (1u << 24) : 0u)
                | ((y0 < 255) ? (1u << 25) : 0u);
    float sprime = (sc + 1.0f) * 0.99609375f;
    __half2 wh = __floats2half2_rn(wx, wy);
    psort[p * NPTS + base[key] + rank] =
        make_float4(__uint_as_float(pk), __builtin_bit_cast(float, wh),
                    sprime, __int_as_float(n));
}

// ---------------- Gather (sorted, XCD-chunk swizzled, 4-pt pipelined) -------
// dot2-first: per corner, dot the lane's 8 fp16 values with the 8 fp16
// Fourier weights (4 x v_dot2_f32_f16), then 4-corner bilerp combine.
// Each wave processes 4 consecutive sorted points, software-pipelined:
// STAGE(i+1)'s feat loads are in flight during WORK(i)'s compute chain.

#define GSTAGE(i)                                                              \
    unsigned pk##i = __float_as_uint(pt##i.x);                                 \
    const ushort* bp##i = fb + (pk##i & 0xFFFFFFu);                            \
    int dx##i = (int)((pk##i >> 16) & 0x100u);                                 \
    int dy##i = (int)((pk##i >> 9) & 0x10000u);                                \
    uint4 e00##i = *(const uint4*)(bp##i);                                     \
    uint4 e01##i = *(const uint4*)(bp##i + dx##i);                             \
    uint4 e10##i = *(const uint4*)(bp##i + dy##i);                             \
    uint4 e11##i = *(const uint4*)(bp##i + dx##i + dy##i);

#define GWORK(i) {                                                             \
    __half2 wh = __builtin_bit_cast(__half2, pt##i.y);                         \
    float wx = __low2float(wh);                                                \
    float wy = __high2float(wh);                                               \
    float a = pt##i.z * coef;                                                  \
    float sn, cs;                                                              \
    sincospif(a, &sn, &cs);                                                    \
    float merged = (q < 16) ? cs : -sn;                                        \
    float partner = __int_as_float(                                            \
        __builtin_amdgcn_ds_swizzle(__float_as_int(merged), 0x041F));          \
    float lo = (l & 1) ? partner : merged;                                     \
    float hi = (l & 1) ? merged : partner;                                     \
    __half2 wp = __floats2half2_rn(lo, hi);                                    \
    unsigned wpi = __builtin_bit_cast(unsigned, wp);                           \
    unsigned w0 = (unsigned)__builtin_amdgcn_ds_swizzle((int)wpi, 0x0010);     \
    unsigned w1 = (unsigned)__builtin_amdgcn_ds_swizzle((int)wpi, 0x0050);     \
    unsigned w2 = (unsigned)__builtin_amdgcn_ds_swizzle((int)wpi, 0x0090);     \
    unsigned w3 = (unsigned)__builtin_amdgcn_ds_swizzle((int)wpi, 0x00D0);     \
    float s00 = dot2f(e00##i.w, w3, dot2f(e00##i.z, w2,                        \
                dot2f(e00##i.y, w1, dot2f(e00##i.x, w0, 0.0f))));              \
    float s01 = dot2f(e01##i.w, w3, dot2f(e01##i.z, w2,                        \
                dot2f(e01##i.y, w1, dot2f(e01##i.x, w0, 0.0f))));              \
    float s10 = dot2f(e10##i.w, w3, dot2f(e10##i.z, w2,                        \
                dot2f(e10##i.y, w1, dot2f(e10##i.x, w0, 0.0f))));              \
    float s11 = dot2f(e11##i.w, w3, dot2f(e11##i.z, w2,                        \
                dot2f(e11##i.y, w1, dot2f(e11##i.x, w0, 0.0f))));              \
    const float INV = 6.103515625e-05f;                                        \
    float wys = wy * INV;                                                      \
    float wyc = INV - wys;                                                     \
    float wxc = 1.0f - wx;                                                     \
    float acc = s00 * (wxc * wyc);                                             \
    acc = fmaf(s01, wx * wyc, acc);                                            \
    acc = fmaf(s10, wxc * wys, acc);                                           \
    acc = fmaf(s11, wx * wys, acc);                                            \
    acc += __int_as_float(                                                     \
        __builtin_amdgcn_ds_swizzle(__float_as_int(acc), 0x401F));             \
    if (q < 16) {                                                              \
        int n = __float_as_int(pt##i.w);                                       \
        atomicAdd(&out[((size_t)n << 4) + q], acc);                            \
    } }

__global__ __launch_bounds__(256) void gather_kernel(const ushort* __restrict__ feat,
                                                     const float4* __restrict__ psort,
                                                     float* __restrict__ out) {
    int t = threadIdx.x;
    int w = t >> 6;
    int l = t & 63;
    int h = l >> 5;                     // point within wave (per iteration)
    int q = l & 31;                     // owns feature bytes 16q..16q+15
    int p = blockIdx.y;
    const ushort* fb = feat + (size_t)p * 16777216 + (q << 3);

    // XCD swizzle: dispatch b -> XCD b%8; give each XCD one contiguous chunk
    int b  = blockIdx.x;                        // 0..8191
    int lb = ((b & 7) << 10) | (b >> 3);        // logical sorted block
    const float4* ps = psort + p * NPTS + (lb << 5) + (w << 1) + h;

    float4 pt0 = ps[0];
    float4 pt1 = ps[8];
    float4 pt2 = ps[16];
    float4 pt3 = ps[24];

    float coef = (float)((1 << (q & 7)) - 1);

    GSTAGE(0)
    GSTAGE(1)
    GWORK(0)
    GSTAGE(2)
    GWORK(1)
    GSTAGE(3)
    GWORK(2)
    GWORK(3)
}

__global__ __launch_bounds__(256) void combine_kernel(const float4* __restrict__ pa,
                                                      float4* __restrict__ out) {
    int i = (blockIdx.x << 8) + threadIdx.x;
    float4 a = pa[i];
    float4 b = pa[i + 1048576];
    float4 c = pa[i + 2097152];
    out[i] = make_float4(a.x + b.x + c.x, a.y + b.y + c.y,
                         a.z + b.z + c.z, a.w + b.w + c.w);
}

extern "C" void kernel_launch(void* const* d_in, const int* in_sizes, int n_in,
                              void* d_out, int out_size, void* d_ws, size_t ws_size,
                              hipStream_t stream) {
    const float* P0  = (const float*)d_in[0];
    const float* P1  = (const float*)d_in[1];
    const float* P2  = (const float*)d_in[2];
    const float* pts = (const float*)d_in[3];
    float* out = (float*)d_out;
    char* ws = (char*)d_ws;

    // ws layout (bytes):
    __half*   feat   = (__half*)ws;                                // 100,663,296
    unsigned* X      = (unsigned*)(ws + 100663296u);               //  50,331,648
    float4*   psort  = (float4*)(ws + 201326592u);                 //  12,582,912
    unsigned* hist   = (unsigned*)(ws + 213909504u);               //       3,072
    unsigned* cursor = (unsigned*)(ws + 213912576u);               //       3,072

    hipMemsetAsync(hist, 0, 3072, stream);
    hipMemsetAsync(out, 0, (size_t)NPTS * 64, stream);             // 16,777,216

    dim3 g1(1024, 3);
    pass1_kernel<<<g1, 512, 0, stream>>>(P0, P1, P2, X);
    dim3 g2(2048, 3);
    pass2_kernel<<<g2, 1024, 0, stream>>>(X, feat);

    dim3 gs(256, 3);
    hist_kernel<<<gs, 1024, 0, stream>>>(pts, hist);
    scan_kernel<<<1, 256, 0, stream>>>(hist, cursor);
    scatter_kernel<<<gs, 1024, 0, stream>>>(pts, cursor, psort);

    dim3 gg(8192, 3);
    gather_kernel<<<gg, 256, 0, stream>>>((const ushort*)feat, psort, out);
}